// Round 3
// baseline (439.148 us; speedup 1.0000x reference)
//
#include <hip/hip_runtime.h>

// MGNConv fused-MFMA, round 3: LDS diet -> 2 blocks/CU (4 waves/SIMD).
//   edge_out[e,k] = sum_{c,ab} hs[e,c] * o[e,ab] * w2[c, ab*8+k]
//   hs = silu(emb@w1/4)/64  (folds both 1/8 path norms)
//   o[e,ab] = attr[e, ab>>4] * z[e, ab&15],  z = cat(x[vi], x[vj])
// Changes this round:
//  - layer-1 computed TRANSPOSED (mfma(w1f, a1)): C holds chans per edge-col;
//    a2 fragments assembled via 32 bpermute + 16 select -> hs LDS buffer GONE
//  - w2t stride 72->64 with XOR swizzle (elem ^= (n&7)<<3), bank-balanced
//  - zt f32 [16][32] unpadded (stride = bank period -> conflict-free both ways)
//  - attr + vj moved to registers, served via shfl from staging lanes
//  - LDS total exactly 81920 B -> 2 blocks/CU; __launch_bounds__(512, 4)

typedef __attribute__((ext_vector_type(8))) short short8;
typedef __attribute__((ext_vector_type(4))) float floatx4;

__device__ inline unsigned short f2bf(float f) {
    union { float f; unsigned u; } v; v.f = f;
    unsigned r = v.u + 0x7FFFu + ((v.u >> 16) & 1u);
    return (unsigned short)(r >> 16);
}

__device__ inline unsigned cvt_pk_bf16(float lo, float hi) {
    unsigned r;
    asm("v_cvt_pk_bf16_f32 %0, %1, %2" : "=v"(r) : "v"(lo), "v"(hi));
    return r;
}

constexpr int TB   = 512;   // 8 waves
constexpr int NBLK = 512;   // 2 blocks per CU (LDS = 81920 B exactly)

__global__ __launch_bounds__(TB, 4) void edge_kernel(
    const float* __restrict__ x,          // [N,8]
    const int*   __restrict__ ei,         // [2,E]
    const float* __restrict__ attr,       // [E,4]
    const float* __restrict__ emb,        // [E,16]
    const float* __restrict__ w1,         // [16,64]
    const float* __restrict__ w2,         // [64,512]
    float* __restrict__ edge_out,         // [E,8]
    float* __restrict__ e_sum,            // [N,8] pre-zeroed
    int E)
{
    // w2 transposed, bf16, XOR-swizzled: s_w2t[n*64 + (k ^ ((n&7)<<3))] = w2[k][n]
    __shared__ __align__(16) unsigned short s_w2t[512 * 64];   // 65536 B
    // z features f32, per wave: [16 feat][32 edge]; stride 32 f32 = bank period
    __shared__ __align__(16) float          s_ztA[8 * 16 * 32]; // 16384 B
    // total = 81920 B exactly -> 2 blocks/CU

    const int tid  = threadIdx.x;
    const int wave = tid >> 6;
    const int lane = tid & 63;
    const int m16  = lane & 15;
    const int quad = lane >> 4;
    const int par  = m16 >> 3;

    // ---- stage w2 transposed+swizzled to bf16 ----
    for (int idx = tid; idx < 512 * 64; idx += TB) {
        const int n = idx & 511, k = idx >> 9;
        s_w2t[n * 64 + (k ^ ((n & 7) << 3))] = f2bf(w2[k * 512 + n]);
    }
    __syncthreads();   // only barrier; steady loop is wave-private

    // ---- layer-1 w1 fragments (zero-padded K 16->32).
    // Same register content serves as the A-operand of the TRANSPOSED
    // layer-1: A[m=chan mt*16+m16][k=quad*8+j] = w1[k][chan].
    short8 w1f[4];
    #pragma unroll
    for (int mt = 0; mt < 4; ++mt) {
        short8 f;
        if (quad < 2) {
            #pragma unroll
            for (int j = 0; j < 8; ++j)
                f[j] = (short)f2bf(w1[(quad * 8 + j) * 64 + mt * 16 + m16]);
        } else {
            #pragma unroll
            for (int j = 0; j < 8; ++j) f[j] = 0;
        }
        w1f[mt] = f;
    }

    float* ztw = s_ztA + wave * 16 * 32;

    const int  wid = blockIdx.x * 8 + wave;
    const int  nw  = NBLK * 8;
    const int  ntiles = E >> 5;   // E divisible by 32 (800000)
    const bool stg = (quad < 2);
    const int  mst = quad * 16 + m16;   // == lane for stg lanes (0..31)

    // a2-gather shuffle source lanes (see derivation in comments below)
    const int srcA = m16 + 16 * ((2 * quad) & 3);
    const int srcB = m16 + 16 * ((2 * quad + 1) & 3);

    // swizzled b2 element offsets
    const int swz = (m16 & 7) << 3;
    const int o0  = (quad * 8) ^ swz;
    const int o1  = o0 ^ 32;

    // ---- pipeline registers (valid on stg lanes) ----
    float4 xi0, xi1, xj0, xj1, a4;
    float4 em0a, em0b, em1a, em1b;
    int viN = 0, vjN = 0, vjC = 0;

    // ---- prologue: tile wid data + ei for tile wid+nw ----
    if (wid < ntiles && stg) {
        const int e0 = (wid << 5) + mst;
        const int vi = ei[e0];
        vjC = ei[E + e0];
        xi0 = *(const float4*)(x + (size_t)vi * 8);
        xi1 = *(const float4*)(x + (size_t)vi * 8 + 4);
        xj0 = *(const float4*)(x + (size_t)vjC * 8);
        xj1 = *(const float4*)(x + (size_t)vjC * 8 + 4);
        a4  = *(const float4*)(attr + (size_t)e0 * 4);
        const float* ep0 = emb + (size_t)((wid << 5) + m16) * 16 + quad * 8;
        em0a = *(const float4*)ep0;
        em0b = *(const float4*)(ep0 + 4);
        const float* ep1 = emb + (size_t)((wid << 5) + 16 + m16) * 16 + quad * 8;
        em1a = *(const float4*)ep1;
        em1b = *(const float4*)(ep1 + 4);
        const int t1 = (wid + nw < ntiles) ? (wid + nw) : wid;
        const int e1 = (t1 << 5) + mst;
        viN = ei[e1];
        vjN = ei[E + e1];
    }

    for (int tile = wid; tile < ntiles; tile += nw) {
        const int base = tile << 5;

        // ---- A: stage z (f32) to wave-private LDS; keep attr/vj in regs ----
        if (stg) {
            ztw[ 0*32+mst]=xi0.x; ztw[ 1*32+mst]=xi0.y;
            ztw[ 2*32+mst]=xi0.z; ztw[ 3*32+mst]=xi0.w;
            ztw[ 4*32+mst]=xi1.x; ztw[ 5*32+mst]=xi1.y;
            ztw[ 6*32+mst]=xi1.z; ztw[ 7*32+mst]=xi1.w;
            ztw[ 8*32+mst]=xj0.x; ztw[ 9*32+mst]=xj0.y;
            ztw[10*32+mst]=xj0.z; ztw[11*32+mst]=xj0.w;
            ztw[12*32+mst]=xj1.x; ztw[13*32+mst]=xj1.y;
            ztw[14*32+mst]=xj1.z; ztw[15*32+mst]=xj1.w;
        }
        const float4 a4cur = a4;   // attr of current tile (source lanes 0..31)
        const int    vjE   = vjC;  // vj of current tile (source lanes 0..31)

        short8 a1[2];
        {
            union { short8 s8; unsigned u[4]; } uu;
            if (stg) {
                uu.u[0] = cvt_pk_bf16(em0a.x, em0a.y);
                uu.u[1] = cvt_pk_bf16(em0a.z, em0a.w);
                uu.u[2] = cvt_pk_bf16(em0b.x, em0b.y);
                uu.u[3] = cvt_pk_bf16(em0b.z, em0b.w);
            } else {
                uu.u[0]=0u; uu.u[1]=0u; uu.u[2]=0u; uu.u[3]=0u;
            }
            a1[0] = uu.s8;
            if (stg) {
                uu.u[0] = cvt_pk_bf16(em1a.x, em1a.y);
                uu.u[1] = cvt_pk_bf16(em1a.z, em1a.w);
                uu.u[2] = cvt_pk_bf16(em1b.x, em1b.y);
                uu.u[3] = cvt_pk_bf16(em1b.z, em1b.w);
            } else {
                uu.u[0]=0u; uu.u[1]=0u; uu.u[2]=0u; uu.u[3]=0u;
            }
            a1[1] = uu.s8;
        }

        // ---- B: issue next-tile loads into the just-consumed registers ----
        {
            const int tn     = tile + nw;
            const int tn_cl  = (tn  < ntiles) ? tn  : tile;
            const int tnn    = tn + nw;
            const int tnn_cl = (tnn < ntiles) ? tnn : tn_cl;
            if (stg) {
                const int en = (tn_cl << 5) + mst;
                vjC = vjN;   // vj of tile tn, needed at next A
                xi0 = *(const float4*)(x + (size_t)viN * 8);
                xi1 = *(const float4*)(x + (size_t)viN * 8 + 4);
                xj0 = *(const float4*)(x + (size_t)vjN * 8);
                xj1 = *(const float4*)(x + (size_t)vjN * 8 + 4);
                a4  = *(const float4*)(attr + (size_t)en * 4);
                const float* ep0 = emb + (size_t)((tn_cl << 5) + m16) * 16 + quad * 8;
                em0a = *(const float4*)ep0;
                em0b = *(const float4*)(ep0 + 4);
                const float* ep1 = emb + (size_t)((tn_cl << 5) + 16 + m16) * 16 + quad * 8;
                em1a = *(const float4*)ep1;
                em1b = *(const float4*)(ep1 + 4);
                const int enn = (tnn_cl << 5) + mst;
                viN = ei[enn];
                vjN = ei[E + enn];
            }
        }

        // ---- C: TRANSPOSED layer-1 MFMA -> silu -> a2 frags via shuffles.
        // C' = w1T @ embT: lane (m16,quad) holds edge s*16+m16,
        // chans {16mt + 4quad + r}. a2[s][qq] needs chans qq*32+quad*8+0..7
        // of the same edge. word w (chans c0=qq*32+quad*8+2w, c0+1) comes from
        // lane (m16, q'=(2quad+(w>>1))&3), reg p[mt'=2qq+(quad>>1)][w&1].
        short8 a2[2][2];
        #pragma unroll
        for (int s = 0; s < 2; ++s) {
            floatx4 c[4];
            #pragma unroll
            for (int mt = 0; mt < 4; ++mt) {
                floatx4 z4 = {0.f, 0.f, 0.f, 0.f};
                c[mt] = __builtin_amdgcn_mfma_f32_16x16x32_bf16(w1f[mt], a1[s], z4, 0, 0, 0);
            }
            unsigned p[4][2];
            #pragma unroll
            for (int mt = 0; mt < 4; ++mt) {
                float sv[4];
                #pragma unroll
                for (int r = 0; r < 4; ++r) {
                    const float u   = c[mt][r] * 0.25f;               // /sqrt(16)
                    const float den = 1.f + __expf(-u);
                    sv[r] = u * __builtin_amdgcn_rcpf(den) * 0.015625f; // /64
                }
                p[mt][0] = cvt_pk_bf16(sv[0], sv[1]);
                p[mt][1] = cvt_pk_bf16(sv[2], sv[3]);
            }
            #pragma unroll
            for (int qq = 0; qq < 2; ++qq) {
                union { short8 s8; unsigned u[4]; } uu;
                #pragma unroll
                for (int w = 0; w < 4; ++w) {
                    const int srcLane = (w < 2) ? srcA : srcB;
                    const unsigned vA = (unsigned)__shfl((int)p[2*qq    ][w & 1], srcLane, 64);
                    const unsigned vB = (unsigned)__shfl((int)p[2*qq + 1][w & 1], srcLane, 64);
                    uu.u[w] = (quad & 2) ? vB : vA;
                }
                a2[s][qq] = uu.s8;
            }
        }

        float eacc[2][4];
        #pragma unroll
        for (int s = 0; s < 2; ++s)
            #pragma unroll
            for (int r = 0; r < 4; ++r) eacc[s][r] = 0.f;

        // ---- D: N loop, defer-attr epilogue; attr via shfl from stg lanes.
        // b_idx = (2t+par)&15 == (2tt+par)&15 (g-independent)
        __builtin_amdgcn_s_setprio(1);
        #pragma unroll 1
        for (int g = 0; g < 4; ++g) {
            const float ag = (g == 0) ? a4cur.x : (g == 1) ? a4cur.y
                           : (g == 2) ? a4cur.z : a4cur.w;
            float av[2][4];
            #pragma unroll
            for (int s = 0; s < 2; ++s)
                #pragma unroll
                for (int r = 0; r < 4; ++r)
                    av[s][r] = __shfl(ag, s * 16 + quad * 4 + r, 64);

            float tacc[2][4];
            #pragma unroll
            for (int s = 0; s < 2; ++s)
                #pragma unroll
                for (int r = 0; r < 4; ++r) tacc[s][r] = 0.f;

            #pragma unroll
            for (int tt = 0; tt < 8; ++tt) {
                const int t = g * 8 + tt;
                const unsigned short* wrow = s_w2t + (16 * t + m16) * 64;
                short8 b2[2];
                b2[0] = *(const short8*)(wrow + o0);
                b2[1] = *(const short8*)(wrow + o1);
                const int b_idx = (2 * tt + par) & 15;
                #pragma unroll
                for (int s = 0; s < 2; ++s) {
                    floatx4 c = {0.f, 0.f, 0.f, 0.f};
                    c = __builtin_amdgcn_mfma_f32_16x16x32_bf16(a2[s][0], b2[0], c, 0, 0, 0);
                    c = __builtin_amdgcn_mfma_f32_16x16x32_bf16(a2[s][1], b2[1], c, 0, 0, 0);
                    const float4 zv = *(const float4*)(ztw + b_idx * 32 + s * 16 + quad * 4);
                    tacc[s][0] = fmaf(c[0], zv.x, tacc[s][0]);
                    tacc[s][1] = fmaf(c[1], zv.y, tacc[s][1]);
                    tacc[s][2] = fmaf(c[2], zv.z, tacc[s][2]);
                    tacc[s][3] = fmaf(c[3], zv.w, tacc[s][3]);
                }
            }
            #pragma unroll
            for (int s = 0; s < 2; ++s)
                #pragma unroll
                for (int r = 0; r < 4; ++r)
                    eacc[s][r] = fmaf(av[s][r], tacc[s][r], eacc[s][r]);
        }
        __builtin_amdgcn_s_setprio(0);

        // ---- E: reduce ab-parity (lanes col and col^8), then write ----
        #pragma unroll
        for (int s = 0; s < 2; ++s)
            #pragma unroll
            for (int r = 0; r < 4; ++r)
                eacc[s][r] += __shfl_xor(eacc[s][r], 8, 64);

        // vj via shfl BEFORE the divergent block (source lanes must be active)
        int vjr[2][4];
        #pragma unroll
        for (int s = 0; s < 2; ++s)
            #pragma unroll
            for (int r = 0; r < 4; ++r)
                vjr[s][r] = __shfl(vjE, s * 16 + quad * 4 + r, 64);

        if (m16 < 8) {
            #pragma unroll
            for (int s = 0; s < 2; ++s) {
                #pragma unroll
                for (int r = 0; r < 4; ++r) {
                    const int e = base + s * 16 + quad * 4 + r;
                    edge_out[(size_t)e * 8 + m16] = eacc[s][r];
                    atomicAdd(e_sum + (size_t)vjr[s][r] * 8 + m16, eacc[s][r]);
                }
            }
        }
    }
}

__global__ __launch_bounds__(256) void node_kernel(
    const float* __restrict__ x,       // [N,8]
    const float* __restrict__ e_sum,   // [N,8]
    const float* __restrict__ w_node,  // [8,8,16]
    float* __restrict__ x_out,         // [N,16]
    int N)
{
    __shared__ float s_w[8 * 8 * 16];
    for (int idx = threadIdx.x; idx < 1024; idx += 256) s_w[idx] = w_node[idx];
    __syncthreads();

    const int n = blockIdx.x * 256 + threadIdx.x;
    if (n >= N) return;

    float xa[8], eb[8];
    #pragma unroll
    for (int a = 0; a < 8; ++a) xa[a] = x[(size_t)n * 8 + a];
    #pragma unroll
    for (int b = 0; b < 8; ++b) eb[b] = e_sum[(size_t)n * 8 + b];

    float out[16];
    #pragma unroll
    for (int k = 0; k < 16; ++k) out[k] = 0.f;

    const float4* wv = (const float4*)s_w;
    #pragma unroll
    for (int a = 0; a < 8; ++a) {
        #pragma unroll
        for (int b = 0; b < 8; ++b) {
            const float t = xa[a] * eb[b] * 0.125f;
            #pragma unroll
            for (int k4 = 0; k4 < 4; ++k4) {
                const float4 w = wv[(a * 8 + b) * 4 + k4];
                out[k4 * 4 + 0] = fmaf(t, w.x, out[k4 * 4 + 0]);
                out[k4 * 4 + 1] = fmaf(t, w.y, out[k4 * 4 + 1]);
                out[k4 * 4 + 2] = fmaf(t, w.z, out[k4 * 4 + 2]);
                out[k4 * 4 + 3] = fmaf(t, w.w, out[k4 * 4 + 3]);
            }
        }
    }

    float4* xo = (float4*)(x_out + (size_t)n * 16);
    #pragma unroll
    for (int k4 = 0; k4 < 4; ++k4)
        xo[k4] = make_float4(out[k4 * 4 + 0], out[k4 * 4 + 1],
                             out[k4 * 4 + 2], out[k4 * 4 + 3]);
}

extern "C" void kernel_launch(void* const* d_in, const int* in_sizes, int n_in,
                              void* d_out, int out_size, void* d_ws, size_t ws_size,
                              hipStream_t stream) {
    const float* x      = (const float*)d_in[0];
    const int*   ei     = (const int*)d_in[1];
    const float* attr   = (const float*)d_in[2];
    const float* emb    = (const float*)d_in[3];
    const float* w1     = (const float*)d_in[4];
    const float* w2     = (const float*)d_in[5];
    const float* w_node = (const float*)d_in[6];

    const int N = in_sizes[0] / 8;   // 50000
    const int E = in_sizes[2] / 4;   // 800000

    float* x_out    = (float*)d_out;                   // [N,16]
    float* edge_out = (float*)d_out + (size_t)N * 16;  // [E,8]
    float* e_sum    = (float*)d_ws;                    // [N,8]

    hipMemsetAsync(e_sum, 0, (size_t)N * 8 * sizeof(float), stream);

    edge_kernel<<<NBLK, TB, 0, stream>>>(x, ei, attr, emb, w1, w2,
                                         edge_out, e_sum, E);

    node_kernel<<<(N + 255) / 256, 256, 0, stream>>>(x, e_sum, w_node, x_out, N);
}

// Round 4
// 205.743 us; speedup vs baseline: 2.1345x; 2.1345x over previous
//
#include <hip/hip_runtime.h>

// MGNConv fused-MFMA, round 4: round-3 structure with the VGPR cap fixed.
//   edge_out[e,k] = sum_{c,ab} hs[e,c] * o[e,ab] * w2[c, ab*8+k]
//   hs = silu(emb@w1/4)/64  (folds both 1/8 path norms)
//   o[e,ab] = attr[e, ab>>4] * z[e, ab&15],  z = cat(x[vi], x[vj])
// Round-3 post-mortem: __launch_bounds__(512,4) was interpreted as 4 BLOCKS/CU
// (CUDA-style) -> 8 waves/EU -> 64-VGPR cap -> massive scratch spills
// (FETCH 44->510 MB). Calibration: (512,2) -> cap 128 (observed 124).
// Changes this round:
//  - __launch_bounds__(TB, 2): VGPR cap 128, no spills; occupancy then
//    LDS-bound at 2 blocks/CU (81920 B x 2 = full 160 KiB) = 4 waves/SIMD
//  - C-phase MFMAs computed in pairs to halve peak c-live registers

typedef __attribute__((ext_vector_type(8))) short short8;
typedef __attribute__((ext_vector_type(4))) float floatx4;

__device__ inline unsigned short f2bf(float f) {
    union { float f; unsigned u; } v; v.f = f;
    unsigned r = v.u + 0x7FFFu + ((v.u >> 16) & 1u);
    return (unsigned short)(r >> 16);
}

__device__ inline unsigned cvt_pk_bf16(float lo, float hi) {
    unsigned r;
    asm("v_cvt_pk_bf16_f32 %0, %1, %2" : "=v"(r) : "v"(lo), "v"(hi));
    return r;
}

constexpr int TB   = 512;   // 8 waves
constexpr int NBLK = 512;   // 2 blocks per CU (LDS = 81920 B exactly)

__global__ __launch_bounds__(TB, 2) void edge_kernel(
    const float* __restrict__ x,          // [N,8]
    const int*   __restrict__ ei,         // [2,E]
    const float* __restrict__ attr,       // [E,4]
    const float* __restrict__ emb,        // [E,16]
    const float* __restrict__ w1,         // [16,64]
    const float* __restrict__ w2,         // [64,512]
    float* __restrict__ edge_out,         // [E,8]
    float* __restrict__ e_sum,            // [N,8] pre-zeroed
    int E)
{
    // w2 transposed, bf16, XOR-swizzled: s_w2t[n*64 + (k ^ ((n&7)<<3))] = w2[k][n]
    __shared__ __align__(16) unsigned short s_w2t[512 * 64];   // 65536 B
    // z features f32, per wave: [16 feat][32 edge]; stride 32 f32 = bank period
    __shared__ __align__(16) float          s_ztA[8 * 16 * 32]; // 16384 B
    // total = 81920 B exactly -> 2 blocks/CU

    const int tid  = threadIdx.x;
    const int wave = tid >> 6;
    const int lane = tid & 63;
    const int m16  = lane & 15;
    const int quad = lane >> 4;
    const int par  = m16 >> 3;

    // ---- stage w2 transposed+swizzled to bf16 ----
    for (int idx = tid; idx < 512 * 64; idx += TB) {
        const int n = idx & 511, k = idx >> 9;
        s_w2t[n * 64 + (k ^ ((n & 7) << 3))] = f2bf(w2[k * 512 + n]);
    }
    __syncthreads();   // only barrier; steady loop is wave-private

    // ---- layer-1 w1 fragments (zero-padded K 16->32).
    // A-operand of the TRANSPOSED layer-1: A[m=chan mt*16+m16][k=quad*8+j] = w1[k][chan].
    short8 w1f[4];
    #pragma unroll
    for (int mt = 0; mt < 4; ++mt) {
        short8 f;
        if (quad < 2) {
            #pragma unroll
            for (int j = 0; j < 8; ++j)
                f[j] = (short)f2bf(w1[(quad * 8 + j) * 64 + mt * 16 + m16]);
        } else {
            #pragma unroll
            for (int j = 0; j < 8; ++j) f[j] = 0;
        }
        w1f[mt] = f;
    }

    float* ztw = s_ztA + wave * 16 * 32;

    const int  wid = blockIdx.x * 8 + wave;
    const int  nw  = NBLK * 8;
    const int  ntiles = E >> 5;   // E divisible by 32 (800000)
    const bool stg = (quad < 2);
    const int  mst = quad * 16 + m16;   // == lane for stg lanes (0..31)

    // a2-gather shuffle source lanes
    const int srcA = m16 + 16 * ((2 * quad) & 3);
    const int srcB = m16 + 16 * ((2 * quad + 1) & 3);

    // swizzled b2 element offsets
    const int swz = (m16 & 7) << 3;
    const int o0  = (quad * 8) ^ swz;
    const int o1  = o0 ^ 32;

    // ---- pipeline registers (valid on stg lanes) ----
    float4 xi0, xi1, xj0, xj1, a4;
    float4 em0a, em0b, em1a, em1b;
    int viN = 0, vjN = 0, vjC = 0;

    // ---- prologue: tile wid data + ei for tile wid+nw ----
    if (wid < ntiles && stg) {
        const int e0 = (wid << 5) + mst;
        const int vi = ei[e0];
        vjC = ei[E + e0];
        xi0 = *(const float4*)(x + (size_t)vi * 8);
        xi1 = *(const float4*)(x + (size_t)vi * 8 + 4);
        xj0 = *(const float4*)(x + (size_t)vjC * 8);
        xj1 = *(const float4*)(x + (size_t)vjC * 8 + 4);
        a4  = *(const float4*)(attr + (size_t)e0 * 4);
        const float* ep0 = emb + (size_t)((wid << 5) + m16) * 16 + quad * 8;
        em0a = *(const float4*)ep0;
        em0b = *(const float4*)(ep0 + 4);
        const float* ep1 = emb + (size_t)((wid << 5) + 16 + m16) * 16 + quad * 8;
        em1a = *(const float4*)ep1;
        em1b = *(const float4*)(ep1 + 4);
        const int t1 = (wid + nw < ntiles) ? (wid + nw) : wid;
        const int e1 = (t1 << 5) + mst;
        viN = ei[e1];
        vjN = ei[E + e1];
    }

    for (int tile = wid; tile < ntiles; tile += nw) {
        const int base = tile << 5;

        // ---- A: stage z (f32) to wave-private LDS; keep attr/vj in regs ----
        if (stg) {
            ztw[ 0*32+mst]=xi0.x; ztw[ 1*32+mst]=xi0.y;
            ztw[ 2*32+mst]=xi0.z; ztw[ 3*32+mst]=xi0.w;
            ztw[ 4*32+mst]=xi1.x; ztw[ 5*32+mst]=xi1.y;
            ztw[ 6*32+mst]=xi1.z; ztw[ 7*32+mst]=xi1.w;
            ztw[ 8*32+mst]=xj0.x; ztw[ 9*32+mst]=xj0.y;
            ztw[10*32+mst]=xj0.z; ztw[11*32+mst]=xj0.w;
            ztw[12*32+mst]=xj1.x; ztw[13*32+mst]=xj1.y;
            ztw[14*32+mst]=xj1.z; ztw[15*32+mst]=xj1.w;
        }
        const float4 a4cur = a4;   // attr of current tile (source lanes 0..31)
        const int    vjE   = vjC;  // vj of current tile (source lanes 0..31)

        short8 a1[2];
        {
            union { short8 s8; unsigned u[4]; } uu;
            if (stg) {
                uu.u[0] = cvt_pk_bf16(em0a.x, em0a.y);
                uu.u[1] = cvt_pk_bf16(em0a.z, em0a.w);
                uu.u[2] = cvt_pk_bf16(em0b.x, em0b.y);
                uu.u[3] = cvt_pk_bf16(em0b.z, em0b.w);
            } else {
                uu.u[0]=0u; uu.u[1]=0u; uu.u[2]=0u; uu.u[3]=0u;
            }
            a1[0] = uu.s8;
            if (stg) {
                uu.u[0] = cvt_pk_bf16(em1a.x, em1a.y);
                uu.u[1] = cvt_pk_bf16(em1a.z, em1a.w);
                uu.u[2] = cvt_pk_bf16(em1b.x, em1b.y);
                uu.u[3] = cvt_pk_bf16(em1b.z, em1b.w);
            } else {
                uu.u[0]=0u; uu.u[1]=0u; uu.u[2]=0u; uu.u[3]=0u;
            }
            a1[1] = uu.s8;
        }

        // ---- B: issue next-tile loads into the just-consumed registers ----
        {
            const int tn     = tile + nw;
            const int tn_cl  = (tn  < ntiles) ? tn  : tile;
            const int tnn    = tn + nw;
            const int tnn_cl = (tnn < ntiles) ? tnn : tn_cl;
            if (stg) {
                const int en = (tn_cl << 5) + mst;
                vjC = vjN;   // vj of tile tn, needed at next A
                xi0 = *(const float4*)(x + (size_t)viN * 8);
                xi1 = *(const float4*)(x + (size_t)viN * 8 + 4);
                xj0 = *(const float4*)(x + (size_t)vjN * 8);
                xj1 = *(const float4*)(x + (size_t)vjN * 8 + 4);
                a4  = *(const float4*)(attr + (size_t)en * 4);
                const float* ep0 = emb + (size_t)((tn_cl << 5) + m16) * 16 + quad * 8;
                em0a = *(const float4*)ep0;
                em0b = *(const float4*)(ep0 + 4);
                const float* ep1 = emb + (size_t)((tn_cl << 5) + 16 + m16) * 16 + quad * 8;
                em1a = *(const float4*)ep1;
                em1b = *(const float4*)(ep1 + 4);
                const int enn = (tnn_cl << 5) + mst;
                viN = ei[enn];
                vjN = ei[E + enn];
            }
        }

        // ---- C: TRANSPOSED layer-1 MFMA -> silu -> a2 frags via shuffles.
        // C' = w1T @ embT: lane (m16,quad) holds edge s*16+m16,
        // chans {16mt + 4quad + r}. a2[s][qq] needs chans qq*32+quad*8+0..7
        // of the same edge. word w (chans c0=qq*32+quad*8+2w, c0+1) comes from
        // lane (m16, q'=(2quad+(w>>1))&3), reg p[mt'=2qq+(quad>>1)][w&1].
        short8 a2[2][2];
        #pragma unroll
        for (int s = 0; s < 2; ++s) {
            unsigned p[4][2];
            // pairs: keeps only 2 C-fragments (8 regs) live at a time
            #pragma unroll
            for (int half = 0; half < 2; ++half) {
                floatx4 c0, c1;
                {
                    floatx4 z4 = {0.f, 0.f, 0.f, 0.f};
                    c0 = __builtin_amdgcn_mfma_f32_16x16x32_bf16(w1f[2*half    ], a1[s], z4, 0, 0, 0);
                    c1 = __builtin_amdgcn_mfma_f32_16x16x32_bf16(w1f[2*half + 1], a1[s], z4, 0, 0, 0);
                }
                #pragma unroll
                for (int h = 0; h < 2; ++h) {
                    const floatx4& c = h ? c1 : c0;
                    float sv[4];
                    #pragma unroll
                    for (int r = 0; r < 4; ++r) {
                        const float u   = c[r] * 0.25f;               // /sqrt(16)
                        const float den = 1.f + __expf(-u);
                        sv[r] = u * __builtin_amdgcn_rcpf(den) * 0.015625f; // /64
                    }
                    p[2*half + h][0] = cvt_pk_bf16(sv[0], sv[1]);
                    p[2*half + h][1] = cvt_pk_bf16(sv[2], sv[3]);
                }
            }
            #pragma unroll
            for (int qq = 0; qq < 2; ++qq) {
                union { short8 s8; unsigned u[4]; } uu;
                #pragma unroll
                for (int w = 0; w < 4; ++w) {
                    const int srcLane = (w < 2) ? srcA : srcB;
                    const unsigned vA = (unsigned)__shfl((int)p[2*qq    ][w & 1], srcLane, 64);
                    const unsigned vB = (unsigned)__shfl((int)p[2*qq + 1][w & 1], srcLane, 64);
                    uu.u[w] = (quad & 2) ? vB : vA;
                }
                a2[s][qq] = uu.s8;
            }
        }

        float eacc[2][4];
        #pragma unroll
        for (int s = 0; s < 2; ++s)
            #pragma unroll
            for (int r = 0; r < 4; ++r) eacc[s][r] = 0.f;

        // ---- D: N loop, defer-attr epilogue; attr via shfl from stg lanes.
        // b_idx = (2t+par)&15 == (2tt+par)&15 (g-independent)
        __builtin_amdgcn_s_setprio(1);
        #pragma unroll 1
        for (int g = 0; g < 4; ++g) {
            const float ag = (g == 0) ? a4cur.x : (g == 1) ? a4cur.y
                           : (g == 2) ? a4cur.z : a4cur.w;
            float av[2][4];
            #pragma unroll
            for (int s = 0; s < 2; ++s)
                #pragma unroll
                for (int r = 0; r < 4; ++r)
                    av[s][r] = __shfl(ag, s * 16 + quad * 4 + r, 64);

            float tacc[2][4];
            #pragma unroll
            for (int s = 0; s < 2; ++s)
                #pragma unroll
                for (int r = 0; r < 4; ++r) tacc[s][r] = 0.f;

            #pragma unroll
            for (int tt = 0; tt < 8; ++tt) {
                const int t = g * 8 + tt;
                const unsigned short* wrow = s_w2t + (16 * t + m16) * 64;
                short8 b2[2];
                b2[0] = *(const short8*)(wrow + o0);
                b2[1] = *(const short8*)(wrow + o1);
                const int b_idx = (2 * tt + par) & 15;
                #pragma unroll
                for (int s = 0; s < 2; ++s) {
                    floatx4 c = {0.f, 0.f, 0.f, 0.f};
                    c = __builtin_amdgcn_mfma_f32_16x16x32_bf16(a2[s][0], b2[0], c, 0, 0, 0);
                    c = __builtin_amdgcn_mfma_f32_16x16x32_bf16(a2[s][1], b2[1], c, 0, 0, 0);
                    const float4 zv = *(const float4*)(ztw + b_idx * 32 + s * 16 + quad * 4);
                    tacc[s][0] = fmaf(c[0], zv.x, tacc[s][0]);
                    tacc[s][1] = fmaf(c[1], zv.y, tacc[s][1]);
                    tacc[s][2] = fmaf(c[2], zv.z, tacc[s][2]);
                    tacc[s][3] = fmaf(c[3], zv.w, tacc[s][3]);
                }
            }
            #pragma unroll
            for (int s = 0; s < 2; ++s)
                #pragma unroll
                for (int r = 0; r < 4; ++r)
                    eacc[s][r] = fmaf(av[s][r], tacc[s][r], eacc[s][r]);
        }
        __builtin_amdgcn_s_setprio(0);

        // ---- E: reduce ab-parity (lanes col and col^8), then write ----
        #pragma unroll
        for (int s = 0; s < 2; ++s)
            #pragma unroll
            for (int r = 0; r < 4; ++r)
                eacc[s][r] += __shfl_xor(eacc[s][r], 8, 64);

        // vj via shfl BEFORE the divergent block (source lanes must be active)
        int vjr[2][4];
        #pragma unroll
        for (int s = 0; s < 2; ++s)
            #pragma unroll
            for (int r = 0; r < 4; ++r)
                vjr[s][r] = __shfl(vjE, s * 16 + quad * 4 + r, 64);

        if (m16 < 8) {
            #pragma unroll
            for (int s = 0; s < 2; ++s) {
                #pragma unroll
                for (int r = 0; r < 4; ++r) {
                    const int e = base + s * 16 + quad * 4 + r;
                    edge_out[(size_t)e * 8 + m16] = eacc[s][r];
                    atomicAdd(e_sum + (size_t)vjr[s][r] * 8 + m16, eacc[s][r]);
                }
            }
        }
    }
}

__global__ __launch_bounds__(256) void node_kernel(
    const float* __restrict__ x,       // [N,8]
    const float* __restrict__ e_sum,   // [N,8]
    const float* __restrict__ w_node,  // [8,8,16]
    float* __restrict__ x_out,         // [N,16]
    int N)
{
    __shared__ float s_w[8 * 8 * 16];
    for (int idx = threadIdx.x; idx < 1024; idx += 256) s_w[idx] = w_node[idx];
    __syncthreads();

    const int n = blockIdx.x * 256 + threadIdx.x;
    if (n >= N) return;

    float xa[8], eb[8];
    #pragma unroll
    for (int a = 0; a < 8; ++a) xa[a] = x[(size_t)n * 8 + a];
    #pragma unroll
    for (int b = 0; b < 8; ++b) eb[b] = e_sum[(size_t)n * 8 + b];

    float out[16];
    #pragma unroll
    for (int k = 0; k < 16; ++k) out[k] = 0.f;

    const float4* wv = (const float4*)s_w;
    #pragma unroll
    for (int a = 0; a < 8; ++a) {
        #pragma unroll
        for (int b = 0; b < 8; ++b) {
            const float t = xa[a] * eb[b] * 0.125f;
            #pragma unroll
            for (int k4 = 0; k4 < 4; ++k4) {
                const float4 w = wv[(a * 8 + b) * 4 + k4];
                out[k4 * 4 + 0] = fmaf(t, w.x, out[k4 * 4 + 0]);
                out[k4 * 4 + 1] = fmaf(t, w.y, out[k4 * 4 + 1]);
                out[k4 * 4 + 2] = fmaf(t, w.z, out[k4 * 4 + 2]);
                out[k4 * 4 + 3] = fmaf(t, w.w, out[k4 * 4 + 3]);
            }
        }
    }

    float4* xo = (float4*)(x_out + (size_t)n * 16);
    #pragma unroll
    for (int k4 = 0; k4 < 4; ++k4)
        xo[k4] = make_float4(out[k4 * 4 + 0], out[k4 * 4 + 1],
                             out[k4 * 4 + 2], out[k4 * 4 + 3]);
}

extern "C" void kernel_launch(void* const* d_in, const int* in_sizes, int n_in,
                              void* d_out, int out_size, void* d_ws, size_t ws_size,
                              hipStream_t stream) {
    const float* x      = (const float*)d_in[0];
    const int*   ei     = (const int*)d_in[1];
    const float* attr   = (const float*)d_in[2];
    const float* emb    = (const float*)d_in[3];
    const float* w1     = (const float*)d_in[4];
    const float* w2     = (const float*)d_in[5];
    const float* w_node = (const float*)d_in[6];

    const int N = in_sizes[0] / 8;   // 50000
    const int E = in_sizes[2] / 4;   // 800000

    float* x_out    = (float*)d_out;                   // [N,16]
    float* edge_out = (float*)d_out + (size_t)N * 16;  // [E,8]
    float* e_sum    = (float*)d_ws;                    // [N,8]

    hipMemsetAsync(e_sum, 0, (size_t)N * 8 * sizeof(float), stream);

    edge_kernel<<<NBLK, TB, 0, stream>>>(x, ei, attr, emb, w1, w2,
                                         edge_out, e_sum, E);

    node_kernel<<<(N + 255) / 256, 256, 0, stream>>>(x, e_sum, w_node, x_out, N);
}